// Round 1
// baseline (41.378 us; speedup 1.0000x reference)
//
#include <hip/hip_runtime.h>

#define BATCH 256
#define SEQ   512
#define DIM   768
#define D4    192   // DIM / 4

// ---------------------------------------------------------------------------
// Kernel 1: per-batch-row segment scan. One wave (64 threads) per row.
// Finds positions of 1st/2nd/3rd SEP token, counts seps, sums attention mask.
// Writes info[b] = { title_n, lead_start, lead_n, 0 }  (n == 0 => use CLS row)
// ---------------------------------------------------------------------------
__global__ __launch_bounds__(64) void seg_scan_kernel(
    const int* __restrict__ ids,     // [BATCH, SEQ]
    const int* __restrict__ amask,   // [BATCH, SEQ]
    const int* __restrict__ sep_tok, // [1]
    int* __restrict__ info)          // [BATCH, 4]
{
    const int b    = blockIdx.x;
    const int lane = threadIdx.x;   // 0..63
    const int sep  = sep_tok[0];

    int nsep = 0;
    int p0 = SEQ, p1 = SEQ, p2 = SEQ;
    int attn = 0;

    // 8 chunks of 64 tokens; every lane ends with identical results
    #pragma unroll
    for (int c = 0; c < SEQ / 64; ++c) {
        const int s = c * 64 + lane;
        const int id = ids[b * SEQ + s];
        const int am = amask[b * SEQ + s];
        unsigned long long msep = __ballot(id == sep);
        unsigned long long mat  = __ballot(am != 0);
        attn += __popcll(mat);
        while (msep) {
            const int bit = __ffsll((long long)msep) - 1;
            const int pos = c * 64 + bit;
            if (nsep == 0)      p0 = pos;
            else if (nsep == 1) p1 = pos;
            else if (nsep == 2) p2 = pos;
            ++nsep;
            msep &= msep - 1;
        }
    }

    if (lane == 0) {
        const bool valid = (nsep >= 2);

        // title: rows [1, p0)
        int tn = p0 - 1;
        if (tn < 0) tn = 0;
        if (!valid) tn = 0;

        // lead: rows [p1+1, lead_end)
        const int lead_start = p1 + 1;
        const int lead_end   = (nsep >= 3) ? p2 : attn;
        int ln = lead_end - lead_start;
        if (ln < 0) ln = 0;
        if (!valid) ln = 0;

        info[b * 4 + 0] = tn;
        info[b * 4 + 1] = lead_start;
        info[b * 4 + 2] = ln;
        info[b * 4 + 3] = 0;
    }
}

// ---------------------------------------------------------------------------
// Kernel 2: pooling. grid = (BATCH, 2 segments, 3 D-chunks), 64 threads.
// Each lane owns one float4 slot; block covers 256 floats of D.
// ---------------------------------------------------------------------------
__global__ __launch_bounds__(64) void seg_pool_kernel(
    const float* __restrict__ hidden, // [BATCH, SEQ, DIM]
    const int*  __restrict__ info,    // [BATCH, 4]
    float* __restrict__ out)          // [2, BATCH, DIM]
{
    const int b     = blockIdx.x;
    const int seg   = blockIdx.y;       // 0 = title, 1 = lead
    const int chunk = blockIdx.z;       // 0..2
    const int t     = threadIdx.x;      // 0..63
    const int d4    = chunk * 64 + t;   // float4 index in [0, 192)

    int start, n;
    if (seg == 0) { start = 1;               n = info[b * 4 + 0]; }
    else          { start = info[b * 4 + 1]; n = info[b * 4 + 2]; }

    const float4* __restrict__ h4 = (const float4*)hidden;
    const size_t base = (size_t)b * (SEQ * D4);

    float4 res;
    if (n > 0) {
        float4 acc = {0.f, 0.f, 0.f, 0.f};
        const int end = start + n;
        #pragma unroll 4
        for (int s = start; s < end; ++s) {
            const float4 v = h4[base + (size_t)s * D4 + d4];
            acc.x += v.x; acc.y += v.y; acc.z += v.z; acc.w += v.w;
        }
        const float fn = (float)n;
        res.x = acc.x / fn; res.y = acc.y / fn;
        res.z = acc.z / fn; res.w = acc.w / fn;
    } else {
        res = h4[base + d4];  // CLS row (s = 0)
    }

    float4* __restrict__ o4 = (float4*)out;
    o4[(size_t)seg * (BATCH * D4) + (size_t)b * D4 + d4] = res;
}

extern "C" void kernel_launch(void* const* d_in, const int* in_sizes, int n_in,
                              void* d_out, int out_size, void* d_ws, size_t ws_size,
                              hipStream_t stream) {
    const float* hidden  = (const float*)d_in[0];
    const int*   ids     = (const int*)d_in[1];
    const int*   amask   = (const int*)d_in[2];
    const int*   sep_tok = (const int*)d_in[3];
    float*       out     = (float*)d_out;
    int*         info    = (int*)d_ws;   // BATCH * 4 ints = 4 KiB

    seg_scan_kernel<<<dim3(BATCH), dim3(64), 0, stream>>>(ids, amask, sep_tok, info);
    seg_pool_kernel<<<dim3(BATCH, 2, 3), dim3(64), 0, stream>>>(hidden, info, out);
}

// Round 2
// 36.790 us; speedup vs baseline: 1.1247x; 1.1247x over previous
//
#include <hip/hip_runtime.h>

#define BATCH 256
#define SEQ   512
#define DIM   768
#define D4    192   // DIM / 4
#define SPL   4     // row-splits per segment (load balance)

// ---------------------------------------------------------------------------
// Kernel 1: per-batch-row segment scan. One wave (64 threads) per row.
// Writes info[b] = { title_n, lead_start, lead_n, 0 }  (n == 0 => use CLS row)
// ---------------------------------------------------------------------------
__global__ __launch_bounds__(64) void seg_scan_kernel(
    const int* __restrict__ ids,     // [BATCH, SEQ]
    const int* __restrict__ amask,   // [BATCH, SEQ]
    const int* __restrict__ sep_tok, // [1]
    int* __restrict__ info)          // [BATCH, 4]
{
    const int b    = blockIdx.x;
    const int lane = threadIdx.x;   // 0..63
    const int sep  = sep_tok[0];

    int nsep = 0;
    int p0 = SEQ, p1 = SEQ, p2 = SEQ;
    int attn = 0;

    #pragma unroll
    for (int c = 0; c < SEQ / 64; ++c) {
        const int s = c * 64 + lane;
        const int id = ids[b * SEQ + s];
        const int am = amask[b * SEQ + s];
        unsigned long long msep = __ballot(id == sep);
        unsigned long long mat  = __ballot(am != 0);
        attn += __popcll(mat);
        while (msep) {
            const int bit = __ffsll((long long)msep) - 1;
            const int pos = c * 64 + bit;
            if (nsep == 0)      p0 = pos;
            else if (nsep == 1) p1 = pos;
            else if (nsep == 2) p2 = pos;
            ++nsep;
            msep &= msep - 1;
        }
    }

    if (lane == 0) {
        const bool valid = (nsep >= 2);

        int tn = p0 - 1;                 // title rows [1, p0)
        if (tn < 0) tn = 0;
        if (!valid) tn = 0;

        const int lead_start = p1 + 1;   // lead rows [p1+1, lead_end)
        const int lead_end   = (nsep >= 3) ? p2 : attn;
        int ln = lead_end - lead_start;
        if (ln < 0) ln = 0;
        if (!valid) ln = 0;

        info[b * 4 + 0] = tn;
        info[b * 4 + 1] = lead_start;
        info[b * 4 + 2] = ln;
        info[b * 4 + 3] = 0;
    }
}

// ---------------------------------------------------------------------------
// Kernel 2: partial pooling. grid = (BATCH, 2, 3 * SPL), 64 threads.
// Each block sums a subrange of the segment's rows over one 256-float D-chunk.
// partial layout: [(b*2+seg)*SPL + split][DIM] floats (sums, not means).
// ---------------------------------------------------------------------------
__global__ __launch_bounds__(64) void seg_pool_partial(
    const float* __restrict__ hidden, // [BATCH, SEQ, DIM]
    const int*  __restrict__ info,    // [BATCH, 4]
    float* __restrict__ partial)      // [BATCH*2*SPL, DIM]
{
    const int b     = blockIdx.x;
    const int seg   = blockIdx.y;       // 0 = title, 1 = lead
    const int z     = blockIdx.z;       // 0..3*SPL-1
    const int chunk = z % 3;
    const int split = z / 3;
    const int t     = threadIdx.x;      // 0..63
    const int d4    = chunk * 64 + t;   // float4 index in [0, 192)

    int start, n;
    if (seg == 0) { start = 1;               n = info[b * 4 + 0]; }
    else          { start = info[b * 4 + 1]; n = info[b * 4 + 2]; }

    const int rows = (n + SPL - 1) / SPL;
    const int s0   = start + split * rows;
    int s1         = s0 + rows;
    const int send = start + n;
    if (s1 > send) s1 = send;

    const float4* __restrict__ h4 = (const float4*)hidden;
    const size_t base = (size_t)b * (SEQ * D4);

    float4 acc = {0.f, 0.f, 0.f, 0.f};
    #pragma unroll 8
    for (int s = s0; s < s1; ++s) {
        const float4 v = h4[base + (size_t)s * D4 + d4];
        acc.x += v.x; acc.y += v.y; acc.z += v.z; acc.w += v.w;
    }

    float4* __restrict__ p4 = (float4*)partial;
    p4[((size_t)(b * 2 + seg) * SPL + split) * D4 + d4] = acc;
}

// ---------------------------------------------------------------------------
// Kernel 3: combine partials, divide, CLS fallback. grid (BATCH, 2), 192 thr.
// ---------------------------------------------------------------------------
__global__ __launch_bounds__(192) void seg_pool_combine(
    const float* __restrict__ hidden,  // [BATCH, SEQ, DIM]
    const int*  __restrict__ info,     // [BATCH, 4]
    const float* __restrict__ partial, // [BATCH*2*SPL, DIM]
    float* __restrict__ out)           // [2, BATCH, DIM]
{
    const int b   = blockIdx.x;
    const int seg = blockIdx.y;
    const int d4  = threadIdx.x;       // 0..191

    const int n = (seg == 0) ? info[b * 4 + 0] : info[b * 4 + 2];

    const float4* __restrict__ p4 = (const float4*)partial;
    const float4* __restrict__ h4 = (const float4*)hidden;

    float4 res;
    if (n > 0) {
        float4 a = {0.f, 0.f, 0.f, 0.f};
        #pragma unroll
        for (int sp = 0; sp < SPL; ++sp) {
            const float4 v = p4[((size_t)(b * 2 + seg) * SPL + sp) * D4 + d4];
            a.x += v.x; a.y += v.y; a.z += v.z; a.w += v.w;
        }
        const float fn = (float)n;
        res.x = a.x / fn; res.y = a.y / fn; res.z = a.z / fn; res.w = a.w / fn;
    } else {
        res = h4[(size_t)b * (SEQ * D4) + d4];  // CLS row
    }

    float4* __restrict__ o4 = (float4*)out;
    o4[(size_t)seg * (BATCH * D4) + (size_t)b * D4 + d4] = res;
}

extern "C" void kernel_launch(void* const* d_in, const int* in_sizes, int n_in,
                              void* d_out, int out_size, void* d_ws, size_t ws_size,
                              hipStream_t stream) {
    const float* hidden  = (const float*)d_in[0];
    const int*   ids     = (const int*)d_in[1];
    const int*   amask   = (const int*)d_in[2];
    const int*   sep_tok = (const int*)d_in[3];
    float*       out     = (float*)d_out;

    int*   info    = (int*)d_ws;                       // 4 KiB
    float* partial = (float*)((char*)d_ws + 4096);     // 256*2*SPL*768*4 = 6.3 MB

    seg_scan_kernel<<<dim3(BATCH), dim3(64), 0, stream>>>(ids, amask, sep_tok, info);
    seg_pool_partial<<<dim3(BATCH, 2, 3 * SPL), dim3(64), 0, stream>>>(hidden, info, partial);
    seg_pool_combine<<<dim3(BATCH, 2), dim3(192), 0, stream>>>(hidden, info, partial, out);
}

// Round 3
// 31.391 us; speedup vs baseline: 1.3182x; 1.1720x over previous
//
#include <hip/hip_runtime.h>

#define BATCH 256
#define SEQ   512
#define DIM   768
#define D4    192   // DIM / 4
#define SPL   4     // row-splits within a block
#define NTHR  (SPL * D4)   // 768 threads = 12 waves

// ---------------------------------------------------------------------------
// Fully fused kernel. grid = (BATCH, 2 segments), 768 threads.
//  - wave 0 scans the batch row's ids/mask (L2-resident) for SEP positions
//  - threads = (split 0..3) x (d4 slot 0..191); each split streams a
//    contiguous quarter of the segment's rows, accumulating one float4
//  - partials combined in LDS, divided by n, CLS fallback, written out
// ---------------------------------------------------------------------------
__global__ __launch_bounds__(NTHR) void seg_pool_fused(
    const float* __restrict__ hidden, // [BATCH, SEQ, DIM]
    const int*  __restrict__ ids,     // [BATCH, SEQ]
    const int*  __restrict__ amask,   // [BATCH, SEQ]
    const int*  __restrict__ sep_tok, // [1]
    float* __restrict__ out)          // [2, BATCH, DIM]
{
    const int b   = blockIdx.x;
    const int seg = blockIdx.y;        // 0 = title, 1 = lead
    const int t   = threadIdx.x;       // 0..767

    __shared__ int    s_info[2];       // start, n
    __shared__ float4 s_red[SPL][D4];  // 12 KiB

    // ---- in-block scan (wave 0 only) ----
    if (t < 64) {
        const int lane = t;
        const int sep  = sep_tok[0];

        int nsep = 0;
        int p0 = SEQ, p1 = SEQ, p2 = SEQ;
        int attn = 0;

        #pragma unroll
        for (int c = 0; c < SEQ / 64; ++c) {
            const int s  = c * 64 + lane;
            const int id = ids[b * SEQ + s];
            const int am = amask[b * SEQ + s];
            unsigned long long msep = __ballot(id == sep);
            unsigned long long mat  = __ballot(am != 0);
            attn += __popcll(mat);
            while (msep) {
                const int bit = __ffsll((long long)msep) - 1;
                const int pos = c * 64 + bit;
                if (nsep == 0)      p0 = pos;
                else if (nsep == 1) p1 = pos;
                else if (nsep == 2) p2 = pos;
                ++nsep;
                msep &= msep - 1;
            }
        }

        if (lane == 0) {
            const bool valid = (nsep >= 2);
            int start, n;
            if (seg == 0) {
                start = 1;
                n = p0 - 1;                       // title rows [1, p0)
                if (n < 0 || !valid) n = 0;
            } else {
                start = p1 + 1;                   // lead rows [p1+1, lead_end)
                const int lead_end = (nsep >= 3) ? p2 : attn;
                n = lead_end - start;
                if (n < 0 || !valid) n = 0;
            }
            s_info[0] = start;
            s_info[1] = n;
        }
    }
    __syncthreads();

    const int start = s_info[0];
    const int n     = s_info[1];

    const int split = t / D4;          // 0..3 (3 whole waves per split)
    const int d4    = t % D4;          // float4 slot

    const float4* __restrict__ h4 = (const float4*)hidden;
    const size_t base = (size_t)b * (SEQ * D4);

    // ---- streaming accumulate over this split's contiguous row chunk ----
    const int chunk = (n + SPL - 1) / SPL;
    const int s0    = start + split * chunk;
    int s1          = s0 + chunk;
    const int send  = start + n;
    if (s1 > send) s1 = send;

    float4 acc = {0.f, 0.f, 0.f, 0.f};
    #pragma unroll 8
    for (int s = s0; s < s1; ++s) {
        const float4 v = h4[base + (size_t)s * D4 + d4];
        acc.x += v.x; acc.y += v.y; acc.z += v.z; acc.w += v.w;
    }
    s_red[split][d4] = acc;
    __syncthreads();

    // ---- combine + divide + CLS fallback + write ----
    if (t < D4) {
        float4 res;
        if (n > 0) {
            const float4 a0 = s_red[0][t];
            const float4 a1 = s_red[1][t];
            const float4 a2 = s_red[2][t];
            const float4 a3 = s_red[3][t];
            const float fn = (float)n;
            res.x = (a0.x + a1.x + a2.x + a3.x) / fn;
            res.y = (a0.y + a1.y + a2.y + a3.y) / fn;
            res.z = (a0.z + a1.z + a2.z + a3.z) / fn;
            res.w = (a0.w + a1.w + a2.w + a3.w) / fn;
        } else {
            res = h4[base + t];   // CLS row (s = 0)
        }
        float4* __restrict__ o4 = (float4*)out;
        o4[(size_t)seg * (BATCH * D4) + (size_t)b * D4 + t] = res;
    }
}

extern "C" void kernel_launch(void* const* d_in, const int* in_sizes, int n_in,
                              void* d_out, int out_size, void* d_ws, size_t ws_size,
                              hipStream_t stream) {
    const float* hidden  = (const float*)d_in[0];
    const int*   ids     = (const int*)d_in[1];
    const int*   amask   = (const int*)d_in[2];
    const int*   sep_tok = (const int*)d_in[3];
    float*       out     = (float*)d_out;

    seg_pool_fused<<<dim3(BATCH, 2), dim3(NTHR), 0, stream>>>(
        hidden, ids, amask, sep_tok, out);
}

// Round 4
// 30.715 us; speedup vs baseline: 1.3471x; 1.0220x over previous
//
#include <hip/hip_runtime.h>

#define BATCH 256
#define SEQ   512
#define DIM   768
#define D4    192          // DIM / 4
#define NW    8            // waves per block = row-splits
#define NTHR  (NW * 64)    // 512 threads
#define ZCH   3            // D chunks of 64 float4 (256 floats) each

// ---------------------------------------------------------------------------
// Fully fused, fine-grained kernel. grid = (BATCH, 2 segments, 3 D-chunks),
// 512 threads = 8 waves.
//  - scan: each wave ballots its own 64-token chunk (ids/mask are L2-hot),
//    thread 0 walks the 8 masks to get sep positions / counts
//  - stream: 8 row-splits x 64 float4-slots; each wave streams a contiguous
//    eighth of the segment's rows over this block's 1KB D-slice
//  - LDS-combine, divide, CLS fallback, write
// ---------------------------------------------------------------------------
__global__ __launch_bounds__(NTHR) void seg_pool_fused(
    const float* __restrict__ hidden, // [BATCH, SEQ, DIM]
    const int*  __restrict__ ids,     // [BATCH, SEQ]
    const int*  __restrict__ amask,   // [BATCH, SEQ]
    const int*  __restrict__ sep_tok, // [1]
    float* __restrict__ out)          // [2, BATCH, DIM]
{
    const int b    = blockIdx.x;
    const int seg  = blockIdx.y;       // 0 = title, 1 = lead
    const int z    = blockIdx.z;       // 0..2 D-chunk
    const int t    = threadIdx.x;      // 0..511
    const int w    = t >> 6;           // wave = row-split 0..7
    const int lane = t & 63;

    __shared__ unsigned long long s_msep[NW];
    __shared__ int    s_att[NW];
    __shared__ int    s_info[2];       // start, n
    __shared__ float4 s_red[NW][64];   // 8 KiB

    // ---- parallel scan: wave w covers tokens [w*64, w*64+64) ----
    {
        const int id = ids[b * SEQ + t];
        const int am = amask[b * SEQ + t];
        const unsigned long long m  = __ballot(id == sep_tok[0]);
        const unsigned long long ma = __ballot(am != 0);
        if (lane == 0) { s_msep[w] = m; s_att[w] = __popcll(ma); }
    }
    __syncthreads();

    if (t == 0) {
        int nsep = 0, p0 = SEQ, p1 = SEQ, p2 = SEQ, attn = 0;
        #pragma unroll
        for (int c = 0; c < NW; ++c) {
            attn += s_att[c];
            unsigned long long mm = s_msep[c];
            while (mm) {
                const int bit = __ffsll((long long)mm) - 1;
                const int pos = c * 64 + bit;
                if (nsep == 0)      p0 = pos;
                else if (nsep == 1) p1 = pos;
                else if (nsep == 2) p2 = pos;
                ++nsep;
                mm &= mm - 1;
            }
        }
        const bool valid = (nsep >= 2);
        int start, n;
        if (seg == 0) {
            start = 1;
            n = p0 - 1;                              // title rows [1, p0)
        } else {
            start = p1 + 1;                          // lead rows [p1+1, lead_end)
            const int lead_end = (nsep >= 3) ? p2 : attn;
            n = lead_end - start;
        }
        if (n < 0 || !valid) n = 0;
        s_info[0] = start;
        s_info[1] = n;
    }
    __syncthreads();

    const int start = s_info[0];
    const int n     = s_info[1];
    const int d4    = z * 64 + lane;   // this block's float4 slot for this lane

    const float4* __restrict__ h4 = (const float4*)hidden;
    const size_t base = (size_t)b * (SEQ * D4);

    // ---- streaming accumulate: wave w takes a contiguous eighth of rows ----
    const int chunk = (n + NW - 1) / NW;
    const int s0    = start + w * chunk;
    int s1          = s0 + chunk;
    const int send  = start + n;
    if (s1 > send) s1 = send;

    float4 acc = {0.f, 0.f, 0.f, 0.f};
    #pragma unroll 8
    for (int s = s0; s < s1; ++s) {
        const float4 v = h4[base + (size_t)s * D4 + d4];
        acc.x += v.x; acc.y += v.y; acc.z += v.z; acc.w += v.w;
    }
    s_red[w][lane] = acc;
    __syncthreads();

    // ---- combine + divide + CLS fallback + write ----
    if (t < 64) {
        float4 res;
        if (n > 0) {
            float4 a = {0.f, 0.f, 0.f, 0.f};
            #pragma unroll
            for (int c = 0; c < NW; ++c) {
                const float4 v = s_red[c][t];
                a.x += v.x; a.y += v.y; a.z += v.z; a.w += v.w;
            }
            const float fn = (float)n;
            res.x = a.x / fn; res.y = a.y / fn;
            res.z = a.z / fn; res.w = a.w / fn;
        } else {
            res = h4[base + d4];       // CLS row (s = 0), this D-slice
        }
        float4* __restrict__ o4 = (float4*)out;
        o4[(size_t)seg * (BATCH * D4) + (size_t)b * D4 + d4] = res;
    }
}

extern "C" void kernel_launch(void* const* d_in, const int* in_sizes, int n_in,
                              void* d_out, int out_size, void* d_ws, size_t ws_size,
                              hipStream_t stream) {
    const float* hidden  = (const float*)d_in[0];
    const int*   ids     = (const int*)d_in[1];
    const int*   amask   = (const int*)d_in[2];
    const int*   sep_tok = (const int*)d_in[3];
    float*       out     = (float*)d_out;

    seg_pool_fused<<<dim3(BATCH, 2, ZCH), dim3(NTHR), 0, stream>>>(
        hidden, ids, amask, sep_tok, out);
}

// Round 5
// 30.390 us; speedup vs baseline: 1.3616x; 1.0107x over previous
//
#include <hip/hip_runtime.h>

#define BATCH 256
#define SEQ   512
#define DIM   768
#define D4    192          // DIM / 4
#define NW    8            // waves per block = row-splits
#define NTHR  (NW * 64)    // 512 threads
#define ZCH   3            // D chunks of 64 float4 (256 floats) each

// ---------------------------------------------------------------------------
// Fused kernel. grid = (BATCH, ZCH, 2) — seg OUTERMOST so that seg==0 (LEAD,
// the big blocks) dispatches first and tiny title blocks backfill the tail.
//  - scan: each wave ballots its 64-token chunk of ids (L2-hot); amask is
//    loaded lazily only if nsep < 3 (rare path)
//  - stream: 8 row-splits x 64 float4-slots, unroll 16 for 16 outstanding
//    1KB loads per wave
//  - LDS-combine, divide, CLS fallback, write
// ---------------------------------------------------------------------------
__global__ __launch_bounds__(NTHR) void seg_pool_fused(
    const float* __restrict__ hidden, // [BATCH, SEQ, DIM]
    const int*  __restrict__ ids,     // [BATCH, SEQ]
    const int*  __restrict__ amask,   // [BATCH, SEQ]
    const int*  __restrict__ sep_tok, // [1]
    float* __restrict__ out)          // [2, BATCH, DIM] (0=title, 1=lead)
{
    const int b    = blockIdx.x;
    const int z    = blockIdx.y;       // 0..2 D-chunk
    const int seg  = blockIdx.z;       // 0 = LEAD (first), 1 = TITLE
    const int t    = threadIdx.x;      // 0..511
    const int w    = t >> 6;           // wave = row-split 0..7
    const int lane = t & 63;

    __shared__ unsigned long long s_msep[NW];
    __shared__ int    s_att[NW];
    __shared__ int    s_info[3];       // start, n, need_mask
    __shared__ float4 s_red[NW][64];   // 8 KiB

    // ---- parallel scan of ids: wave w covers tokens [w*64, w*64+64) ----
    {
        const int id = ids[b * SEQ + t];
        const unsigned long long m = __ballot(id == sep_tok[0]);
        if (lane == 0) s_msep[w] = m;
    }
    __syncthreads();

    if (t == 0) {
        int nsep = 0, p0 = SEQ, p1 = SEQ, p2 = SEQ;
        #pragma unroll
        for (int c = 0; c < NW; ++c) {
            unsigned long long mm = s_msep[c];
            while (mm) {
                const int bit = __ffsll((long long)mm) - 1;
                const int pos = c * 64 + bit;
                if (nsep == 0)      p0 = pos;
                else if (nsep == 1) p1 = pos;
                else if (nsep == 2) p2 = pos;
                ++nsep;
                mm &= mm - 1;
            }
        }
        const bool valid = (nsep >= 2);
        if (seg == 1) {                       // TITLE: rows [1, p0)
            int n = p0 - 1;
            if (n < 0 || !valid) n = 0;
            s_info[0] = 1; s_info[1] = n; s_info[2] = 0;
        } else if (nsep >= 3) {               // LEAD, common: rows [p1+1, p2)
            int n = p2 - (p1 + 1);
            if (n < 0) n = 0;
            s_info[0] = p1 + 1; s_info[1] = n; s_info[2] = 0;
        } else {                              // LEAD, rare: need attn length
            s_info[0] = p1 + 1;
            s_info[1] = valid ? -1 : 0;       // -1 => compute from attn
            s_info[2] = valid ? 1 : 0;
        }
    }
    __syncthreads();

    if (s_info[2]) {                          // rare path: popcount amask
        const int am = amask[b * SEQ + t];
        const unsigned long long ma = __ballot(am != 0);
        if (lane == 0) s_att[w] = __popcll(ma);
        __syncthreads();
        if (t == 0) {
            int attn = 0;
            #pragma unroll
            for (int c = 0; c < NW; ++c) attn += s_att[c];
            int n = attn - s_info[0];         // lead_end(=attn) - lead_start
            if (n < 0) n = 0;
            s_info[1] = n;
        }
        __syncthreads();
    }

    const int start = s_info[0];
    const int n     = s_info[1];
    const int d4    = z * 64 + lane;

    const float4* __restrict__ h4 = (const float4*)hidden;
    const size_t base = (size_t)b * (SEQ * D4);

    // ---- streaming accumulate: wave w takes a contiguous eighth of rows ----
    const int chunk = (n + NW - 1) / NW;
    const int s0    = start + w * chunk;
    int s1          = s0 + chunk;
    const int send  = start + n;
    if (s1 > send) s1 = send;

    float4 acc = {0.f, 0.f, 0.f, 0.f};
    #pragma unroll 16
    for (int s = s0; s < s1; ++s) {
        const float4 v = h4[base + (size_t)s * D4 + d4];
        acc.x += v.x; acc.y += v.y; acc.z += v.z; acc.w += v.w;
    }
    s_red[w][lane] = acc;
    __syncthreads();

    // ---- combine + divide + CLS fallback + write ----
    if (t < 64) {
        float4 res;
        if (n > 0) {
            float4 a = {0.f, 0.f, 0.f, 0.f};
            #pragma unroll
            for (int c = 0; c < NW; ++c) {
                const float4 v = s_red[c][t];
                a.x += v.x; a.y += v.y; a.z += v.z; a.w += v.w;
            }
            const float fn = (float)n;
            res.x = a.x / fn; res.y = a.y / fn;
            res.z = a.z / fn; res.w = a.w / fn;
        } else {
            res = h4[base + d4];              // CLS row (s = 0), this D-slice
        }
        // output order: 0 = title, 1 = lead; our seg: 0 = lead, 1 = title
        const int seg_out = 1 - seg;
        float4* __restrict__ o4 = (float4*)out;
        o4[(size_t)seg_out * (BATCH * D4) + (size_t)b * D4 + d4] = res;
    }
}

extern "C" void kernel_launch(void* const* d_in, const int* in_sizes, int n_in,
                              void* d_out, int out_size, void* d_ws, size_t ws_size,
                              hipStream_t stream) {
    const float* hidden  = (const float*)d_in[0];
    const int*   ids     = (const int*)d_in[1];
    const int*   amask   = (const int*)d_in[2];
    const int*   sep_tok = (const int*)d_in[3];
    float*       out     = (float*)d_out;

    seg_pool_fused<<<dim3(BATCH, ZCH, 2), dim3(NTHR), 0, stream>>>(
        hidden, ids, amask, sep_tok, out);
}

// Round 6
// 30.112 us; speedup vs baseline: 1.3741x; 1.0092x over previous
//
#include <hip/hip_runtime.h>

#define BATCH 256
#define SEQ   512
#define DIM   768
#define D4    192           // DIM / 4
#define NWV   12            // waves per block
#define NTHR  (NWV * 64)    // 768 threads

// ---------------------------------------------------------------------------
// Fused kernel, full-row-per-wave. grid = (BATCH, 2 segments), 768 threads.
// All 512 blocks resident simultaneously (2/CU) -> zero dispatch tail.
//  - scan: waves 0..7 ballot their 64-token chunk of ids; amask lazy
//  - stream: wave w takes rows start+w, start+w+12, ...; each row read as
//    3 consecutive 1KB wave-loads (full 3KB row -> single DRAM page pass)
//  - LDS combine (12 partials), divide, CLS fallback, write
// ---------------------------------------------------------------------------
__global__ __launch_bounds__(NTHR) void seg_pool_fused(
    const float* __restrict__ hidden, // [BATCH, SEQ, DIM]
    const int*  __restrict__ ids,     // [BATCH, SEQ]
    const int*  __restrict__ amask,   // [BATCH, SEQ]
    const int*  __restrict__ sep_tok, // [1]
    float* __restrict__ out)          // [2, BATCH, DIM] (0=title, 1=lead)
{
    const int b    = blockIdx.x;
    const int seg  = blockIdx.y;       // 0 = LEAD, 1 = TITLE
    const int t    = threadIdx.x;      // 0..767
    const int w    = t >> 6;           // wave 0..11
    const int lane = t & 63;

    __shared__ unsigned long long s_msep[8];
    __shared__ int    s_att[8];
    __shared__ int    s_info[3];       // start, n, need_mask
    __shared__ float4 s_red[NWV][D4];  // 36 KiB

    // ---- parallel scan of ids: waves 0..7 cover tokens [w*64, w*64+64) ----
    if (t < SEQ) {
        const int id = ids[b * SEQ + t];
        const unsigned long long m = __ballot(id == sep_tok[0]);
        if (lane == 0) s_msep[w] = m;
    }
    __syncthreads();

    if (t == 0) {
        int nsep = 0, p0 = SEQ, p1 = SEQ, p2 = SEQ;
        #pragma unroll
        for (int c = 0; c < 8; ++c) {
            unsigned long long mm = s_msep[c];
            while (mm) {
                const int bit = __ffsll((long long)mm) - 1;
                const int pos = c * 64 + bit;
                if (nsep == 0)      p0 = pos;
                else if (nsep == 1) p1 = pos;
                else if (nsep == 2) p2 = pos;
                ++nsep;
                mm &= mm - 1;
            }
        }
        const bool valid = (nsep >= 2);
        if (seg == 1) {                       // TITLE: rows [1, p0)
            int n = p0 - 1;
            if (n < 0 || !valid) n = 0;
            s_info[0] = 1; s_info[1] = n; s_info[2] = 0;
        } else if (nsep >= 3) {               // LEAD, common: rows [p1+1, p2)
            int n = p2 - (p1 + 1);
            if (n < 0) n = 0;
            s_info[0] = p1 + 1; s_info[1] = n; s_info[2] = 0;
        } else {                              // LEAD, rare: need attn length
            s_info[0] = p1 + 1;
            s_info[1] = 0;
            s_info[2] = valid ? 1 : 0;
        }
    }
    __syncthreads();

    if (s_info[2]) {                          // rare path: popcount amask
        if (t < SEQ) {
            const int am = amask[b * SEQ + t];
            const unsigned long long ma = __ballot(am != 0);
            if (lane == 0) s_att[w] = __popcll(ma);
        }
        __syncthreads();
        if (t == 0) {
            int attn = 0;
            #pragma unroll
            for (int c = 0; c < 8; ++c) attn += s_att[c];
            int n = attn - s_info[0];
            if (n < 0) n = 0;
            s_info[1] = n;
        }
        __syncthreads();
    }

    const int start = s_info[0];
    const int n     = s_info[1];

    const float4* __restrict__ h4 = (const float4*)hidden;
    const size_t base = (size_t)b * (SEQ * D4);

    // ---- stream: wave w reads FULL rows start+w, start+w+NWV, ... ----
    float4 a0 = {0.f, 0.f, 0.f, 0.f};
    float4 a1 = {0.f, 0.f, 0.f, 0.f};
    float4 a2 = {0.f, 0.f, 0.f, 0.f};

    const int nr = (n > w) ? (n - w + NWV - 1) / NWV : 0;  // rows for wave w
    int s = start + w;
    #pragma unroll 4
    for (int k = 0; k < nr; ++k, s += NWV) {
        const float4* __restrict__ r = h4 + base + (size_t)s * D4;
        const float4 v0 = r[lane];
        const float4 v1 = r[lane + 64];
        const float4 v2 = r[lane + 128];
        a0.x += v0.x; a0.y += v0.y; a0.z += v0.z; a0.w += v0.w;
        a1.x += v1.x; a1.y += v1.y; a1.z += v1.z; a1.w += v1.w;
        a2.x += v2.x; a2.y += v2.y; a2.z += v2.z; a2.w += v2.w;
    }
    s_red[w][lane]       = a0;
    s_red[w][lane + 64]  = a1;
    s_red[w][lane + 128] = a2;
    __syncthreads();

    // ---- combine + divide + CLS fallback + write ----
    if (t < D4) {
        float4 res;
        if (n > 0) {
            float4 a = {0.f, 0.f, 0.f, 0.f};
            #pragma unroll
            for (int c = 0; c < NWV; ++c) {
                const float4 v = s_red[c][t];
                a.x += v.x; a.y += v.y; a.z += v.z; a.w += v.w;
            }
            const float fn = (float)n;
            res.x = a.x / fn; res.y = a.y / fn;
            res.z = a.z / fn; res.w = a.w / fn;
        } else {
            res = h4[base + t];               // CLS row (s = 0)
        }
        // output order: 0 = title, 1 = lead; our seg: 0 = lead, 1 = title
        const int seg_out = 1 - seg;
        float4* __restrict__ o4 = (float4*)out;
        o4[(size_t)seg_out * (BATCH * D4) + (size_t)b * D4 + t] = res;
    }
}

extern "C" void kernel_launch(void* const* d_in, const int* in_sizes, int n_in,
                              void* d_out, int out_size, void* d_ws, size_t ws_size,
                              hipStream_t stream) {
    const float* hidden  = (const float*)d_in[0];
    const int*   ids     = (const int*)d_in[1];
    const int*   amask   = (const int*)d_in[2];
    const int*   sep_tok = (const int*)d_in[3];
    float*       out     = (float*)d_out;

    seg_pool_fused<<<dim3(BATCH, 2), dim3(NTHR), 0, stream>>>(
        hidden, ids, amask, sep_tok, out);
}